// Round 5
// baseline (272.470 us; speedup 1.0000x reference)
//
#include <hip/hip_runtime.h>
#include <stdint.h>

#define N_NODES 50000
#define N_EDGES 800000
#define D_IN    256
#define D_H     64
#define D_O     40
#define D_OP    48   // h2 padded row stride

// CSR build geometry: 64 blocks, each owns a 12500-edge slice; node space
// covered in 4 LDS passes of 12500 bins (50 KB LDS, no global atomics).
#define NB_H  64
#define NT_H  512
#define EPB   ((N_EDGES + NB_H - 1) / NB_H)   // 12500
#define BINS  12500
#define NPASS 4

typedef unsigned int u32;

// ---------------- per-block partial histogram (LDS atomics only) ----------------

__global__ void __launch_bounds__(NT_H) hist_part_kernel(const int* __restrict__ idx,
                                                         u32* __restrict__ part) {
    __shared__ u32 bins[BINS];
    const int b = blockIdx.x;
    const int e0 = b * EPB;
    const int e1 = (e0 + EPB < N_EDGES) ? e0 + EPB : N_EDGES;
    for (int pass = 0; pass < NPASS; ++pass) {
        const int base = pass * BINS;
        for (int i = threadIdx.x; i < BINS; i += NT_H) bins[i] = 0;
        __syncthreads();
        for (int e = e0 + threadIdx.x; e < e1; e += NT_H) {
            int v = idx[e] - base;
            if ((u32)v < (u32)BINS) atomicAdd(&bins[v], 1u);
        }
        __syncthreads();
        for (int i = threadIdx.x; i < BINS; i += NT_H)
            part[(size_t)b * N_NODES + base + i] = bins[i];
        __syncthreads();
    }
}

// ---------------- norm_out = rsqrt(max(col-sum of src partials, 1)) ----------------

__global__ void reduce_nout_kernel(const u32* __restrict__ part, float* __restrict__ norm_out) {
    int n = blockIdx.x * blockDim.x + threadIdx.x;
    if (n < N_NODES) {
        u32 acc = 0;
        for (int b = 0; b < NB_H; ++b) acc += part[(size_t)b * N_NODES + n];
        norm_out[n] = rsqrtf(fmaxf((float)acc, 1.0f));
    }
}

// ---------------- exclusive column-prefix of dst partials (-> off), cnt_in, norm_in ----------------

__global__ void colscan_kernel(u32* __restrict__ part, int* __restrict__ cnt_in,
                               float* __restrict__ norm_in) {
    int n = blockIdx.x * blockDim.x + threadIdx.x;
    if (n < N_NODES) {
        u32 acc = 0;
        for (int b = 0; b < NB_H; ++b) {
            size_t i = (size_t)b * N_NODES + n;
            u32 t = part[i];
            part[i] = acc;
            acc += t;
        }
        cnt_in[n] = (int)acc;
        norm_in[n] = rsqrtf(fmaxf((float)acc, 1.0f));
    }
}

// ---------------- exclusive scan of cnt_in -> start[] ----------------

#define SCAN_NB ((N_NODES + 255) / 256)   // 196

__global__ void scan1_kernel(const int* __restrict__ cnt, int* __restrict__ start,
                             int* __restrict__ blocksum) {
    __shared__ int tmp[256];
    int i = blockIdx.x * 256 + threadIdx.x;
    int v = (i < N_NODES) ? cnt[i] : 0;
    tmp[threadIdx.x] = v;
    __syncthreads();
    for (int off = 1; off < 256; off <<= 1) {
        int t = (threadIdx.x >= off) ? tmp[threadIdx.x - off] : 0;
        __syncthreads();
        tmp[threadIdx.x] += t;
        __syncthreads();
    }
    if (i < N_NODES) start[i] = tmp[threadIdx.x] - v;
    if (threadIdx.x == 255) blocksum[blockIdx.x] = tmp[255];
}

__global__ void scan2_kernel(int* __restrict__ blocksum) {
    __shared__ int tmp[256];
    int v = (threadIdx.x < SCAN_NB) ? blocksum[threadIdx.x] : 0;
    tmp[threadIdx.x] = v;
    __syncthreads();
    for (int off = 1; off < 256; off <<= 1) {
        int t = (threadIdx.x >= off) ? tmp[threadIdx.x - off] : 0;
        __syncthreads();
        tmp[threadIdx.x] += t;
        __syncthreads();
    }
    blocksum[threadIdx.x] = tmp[threadIdx.x] - v;
}

__global__ void scan3_kernel(int* __restrict__ start, const int* __restrict__ blocksum) {
    int i = blockIdx.x * 256 + threadIdx.x;
    if (i < N_NODES) start[i] += blocksum[i >> 8];
    if (i == 0) start[N_NODES] = N_EDGES;
}

// ---------------- scatter edges into CSR order (LDS cursors, no global atomics) ----------------

__global__ void __launch_bounds__(NT_H) scatter2_kernel(const int* __restrict__ src,
                                                        const int* __restrict__ dst,
                                                        const int* __restrict__ start,
                                                        const u32* __restrict__ off,
                                                        int* __restrict__ ssrc) {
    __shared__ u32 cur[BINS];
    const int b = blockIdx.x;
    const int e0 = b * EPB;
    const int e1 = (e0 + EPB < N_EDGES) ? e0 + EPB : N_EDGES;
    for (int pass = 0; pass < NPASS; ++pass) {
        const int base = pass * BINS;
        for (int i = threadIdx.x; i < BINS; i += NT_H) cur[i] = 0;
        __syncthreads();
        for (int e = e0 + threadIdx.x; e < e1; e += NT_H) {
            int d = dst[e];
            int r = d - base;
            if ((u32)r < (u32)BINS) {
                u32 c = atomicAdd(&cur[r], 1u);
                int pos = start[d] + (int)off[(size_t)b * N_NODES + d] + (int)c;
                ssrc[pos] = src[e];
            }
        }
        __syncthreads();
    }
}

// ---------------- W2 zero-padded to [64][48] ----------------

__global__ void padw2_kernel(const float* __restrict__ W2, float* __restrict__ W2p) {
    int i = blockIdx.x * blockDim.x + threadIdx.x;
    if (i < D_H * D_OP) {
        int k = i / D_OP, j = i - k * D_OP;
        W2p[i] = (j < D_O) ? W2[k * D_O + j] : 0.0f;
    }
}

// ---------------- GEMM1: h1[n][j] = norm_out[n] * dot(feat[n,:], W1[:,j]) ----------------

#define G1S 33

__global__ void __launch_bounds__(256, 8) gemm1_kernel(const float* __restrict__ feat,
                                                       const float* __restrict__ W1,
                                                       const float* __restrict__ norm_out,
                                                       float* __restrict__ h1) {
    __shared__ float tile[64 * G1S];
    const int tid = threadIdx.x;
    const int lane = tid & 63;
    const int cbase = __builtin_amdgcn_readfirstlane((tid >> 6) * 16);
    const int n0 = blockIdx.x * 64;

    float acc[16];
#pragma unroll
    for (int c = 0; c < 16; ++c) acc[c] = 0.0f;

    for (int k0 = 0; k0 < D_IN; k0 += 32) {
        __syncthreads();
#pragma unroll
        for (int it = 0; it < 2; ++it) {
            int idx = it * 256 + tid;
            int row = idx >> 3;
            int q = idx & 7;
            int nr = n0 + row; if (nr >= N_NODES) nr = N_NODES - 1;
            float4 v = *(const float4*)(feat + nr * D_IN + k0 + q * 4);
            float* dp = &tile[row * G1S + q * 4];
            dp[0] = v.x; dp[1] = v.y; dp[2] = v.z; dp[3] = v.w;
        }
        __syncthreads();
        const float* wp = W1 + k0 * D_H + cbase;
#pragma unroll
        for (int kk = 0; kk < 32; ++kk) {
            float f = tile[lane * G1S + kk];
#pragma unroll
            for (int c = 0; c < 16; ++c)
                acc[c] = fmaf(f, wp[kk * D_H + c], acc[c]);
        }
    }
    int n = n0 + lane;
    if (n < N_NODES) {
        float no = norm_out[n];
        float* hp = h1 + n * D_H + cbase;
#pragma unroll
        for (int c0 = 0; c0 < 16; c0 += 4) {
            float4 r = make_float4(acc[c0] * no, acc[c0 + 1] * no,
                                   acc[c0 + 2] * no, acc[c0 + 3] * no);
            *(float4*)(hp + c0) = r;
        }
    }
}

// ---------------- agg1: g[n][:] = relu(sum_e h1[ssrc[e]][:] * ni + b1) * no ----------------

__global__ void __launch_bounds__(256) agg1_kernel(const int* __restrict__ start,
                                                   const int* __restrict__ ssrc,
                                                   const float* __restrict__ h1,
                                                   const float* __restrict__ norm_in,
                                                   const float* __restrict__ norm_out,
                                                   const float* __restrict__ b1,
                                                   float* __restrict__ g) {
    const int lane = threadIdx.x & 63;
    const int q = lane & 15;
    const int t = lane >> 4;
    const int wave = (int)((blockIdx.x * blockDim.x + threadIdx.x) >> 6);
    const int nwaves = (int)((gridDim.x * blockDim.x) >> 6);

    const float4 bq = *(const float4*)&b1[q * 4];

    for (int n = wave; n < N_NODES; n += nwaves) {
        int beg = __builtin_amdgcn_readfirstlane(start[n]);
        int end = __builtin_amdgcn_readfirstlane(start[n + 1]);
        float4 acc = make_float4(0.f, 0.f, 0.f, 0.f);
        for (int e = beg + t; e < end; e += 4) {
            int s = ssrc[e];
            float4 v = *(const float4*)(h1 + s * D_H + q * 4);
            acc.x += v.x; acc.y += v.y; acc.z += v.z; acc.w += v.w;
        }
        acc.x += __shfl_xor(acc.x, 16); acc.y += __shfl_xor(acc.y, 16);
        acc.z += __shfl_xor(acc.z, 16); acc.w += __shfl_xor(acc.w, 16);
        acc.x += __shfl_xor(acc.x, 32); acc.y += __shfl_xor(acc.y, 32);
        acc.z += __shfl_xor(acc.z, 32); acc.w += __shfl_xor(acc.w, 32);
        if (t == 0) {
            float ni = norm_in[n], no = norm_out[n];
            float4 r;
            r.x = fmaxf(fmaf(acc.x, ni, bq.x), 0.f) * no;
            r.y = fmaxf(fmaf(acc.y, ni, bq.y), 0.f) * no;
            r.z = fmaxf(fmaf(acc.z, ni, bq.z), 0.f) * no;
            r.w = fmaxf(fmaf(acc.w, ni, bq.w), 0.f) * no;
            *(float4*)(g + n * D_H + q * 4) = r;
        }
    }
}

// ---------------- GEMM2: h2[n][0:48] = dot(g[n,:64], W2p[:,0:48]) ----------------

__global__ void __launch_bounds__(256, 8) gemm2_kernel(const float* __restrict__ g,
                                                       const float* __restrict__ W2p,
                                                       float* __restrict__ h2) {
    __shared__ float tile[64 * G1S];
    const int tid = threadIdx.x;
    const int lane = tid & 63;
    const int cbase = __builtin_amdgcn_readfirstlane((tid >> 6) * 12);
    const int n0 = blockIdx.x * 64;

    float acc[12];
#pragma unroll
    for (int c = 0; c < 12; ++c) acc[c] = 0.0f;

    for (int k0 = 0; k0 < D_H; k0 += 32) {
        __syncthreads();
#pragma unroll
        for (int it = 0; it < 2; ++it) {
            int idx = it * 256 + tid;
            int row = idx >> 3;
            int q = idx & 7;
            int nr = n0 + row; if (nr >= N_NODES) nr = N_NODES - 1;
            float4 v = *(const float4*)(g + nr * D_H + k0 + q * 4);
            float* dp = &tile[row * G1S + q * 4];
            dp[0] = v.x; dp[1] = v.y; dp[2] = v.z; dp[3] = v.w;
        }
        __syncthreads();
        const float* wp = W2p + k0 * D_OP + cbase;
#pragma unroll
        for (int kk = 0; kk < 32; ++kk) {
            float f = tile[lane * G1S + kk];
#pragma unroll
            for (int c = 0; c < 12; ++c)
                acc[c] = fmaf(f, wp[kk * D_OP + c], acc[c]);
        }
    }
    int n = n0 + lane;
    if (n < N_NODES) {
        float* hp = h2 + n * D_OP + cbase;
#pragma unroll
        for (int c0 = 0; c0 < 12; c0 += 4) {
            float4 r = make_float4(acc[c0], acc[c0 + 1], acc[c0 + 2], acc[c0 + 3]);
            *(float4*)(hp + c0) = r;
        }
    }
}

// ---------------- agg2: out[n][:] = (sum_e h2[ssrc[e]][:]) * ni + b2 ----------------

__global__ void __launch_bounds__(256) agg2_kernel(const int* __restrict__ start,
                                                   const int* __restrict__ ssrc,
                                                   const float* __restrict__ h2,
                                                   const float* __restrict__ norm_in,
                                                   const float* __restrict__ b2,
                                                   float* __restrict__ out) {
    const int lane = threadIdx.x & 63;
    const int q = lane % 12;
    const int t = lane / 12;           // 0..5; t==5 idle
    const int wave = (int)((blockIdx.x * blockDim.x + threadIdx.x) >> 6);
    const int nwaves = (int)((gridDim.x * blockDim.x) >> 6);

    for (int n = wave; n < N_NODES; n += nwaves) {
        int beg = __builtin_amdgcn_readfirstlane(start[n]);
        int end = __builtin_amdgcn_readfirstlane(start[n + 1]);
        float4 acc = make_float4(0.f, 0.f, 0.f, 0.f);
        if (t < 5) {
            for (int e = beg + t; e < end; e += 5) {
                int s = ssrc[e];
                float4 v = *(const float4*)(h2 + s * D_OP + q * 4);
                acc.x += v.x; acc.y += v.y; acc.z += v.z; acc.w += v.w;
            }
        }
        float sx = acc.x, sy = acc.y, sz = acc.z, sw = acc.w;
#pragma unroll
        for (int o = 1; o < 5; ++o) {
            sx += __shfl(acc.x, lane + o * 12, 64);
            sy += __shfl(acc.y, lane + o * 12, 64);
            sz += __shfl(acc.z, lane + o * 12, 64);
            sw += __shfl(acc.w, lane + o * 12, 64);
        }
        if (lane < 10) {
            float ni = norm_in[n];
            float4 bq = *(const float4*)&b2[lane * 4];
            float4 r;
            r.x = fmaf(sx, ni, bq.x);
            r.y = fmaf(sy, ni, bq.y);
            r.z = fmaf(sz, ni, bq.z);
            r.w = fmaf(sw, ni, bq.w);
            *(float4*)(out + (size_t)n * D_O + lane * 4) = r;
        }
    }
}

// ----------------------------------------------------------------------------

static inline char* alignup(char* p, size_t a) {
    return (char*)(((uintptr_t)p + a - 1) & ~(uintptr_t)(a - 1));
}

extern "C" void kernel_launch(void* const* d_in, const int* in_sizes, int n_in,
                              void* d_out, int out_size, void* d_ws, size_t ws_size,
                              hipStream_t stream) {
    const float* feat = (const float*)d_in[0];
    const int*   src  = (const int*)d_in[1];
    const int*   dst  = (const int*)d_in[2];
    const float* W1   = (const float*)d_in[3];
    const float* b1   = (const float*)d_in[4];
    const float* W2   = (const float*)d_in[5];
    const float* b2   = (const float*)d_in[6];
    float* out = (float*)d_out;

    char* p = alignup((char*)d_ws, 256);
    int*   cnt_in   = (int*)p;    p = alignup(p + N_NODES * 4, 256);
    int*   start    = (int*)p;    p = alignup(p + (N_NODES + 1) * 4, 256);
    int*   blocksum = (int*)p;    p = alignup(p + 256 * 4, 256);
    float* norm_out = (float*)p;  p = alignup(p + N_NODES * 4, 256);
    float* norm_in  = (float*)p;  p = alignup(p + N_NODES * 4, 256);
    float* W2p      = (float*)p;  p = alignup(p + D_H * D_OP * 4, 256);
    int*   ssrc     = (int*)p;    p = alignup(p + N_EDGES * 4, 256);
    float* h1       = (float*)p;  p = alignup(p + (size_t)N_NODES * D_H * 4, 256);
    float* g        = (float*)p;  p = alignup(p + (size_t)N_NODES * D_H * 4, 256);
    float* h2       = h1;         // h1 dead after agg1

    // partial-count matrices alias the (not-yet-used) h1/g regions:
    // part_src dead after reduce_nout (before gemm1 writes h1);
    // part_dst (= off) dead after scatter2 (before agg1 writes g).
    u32* part_src = (u32*)h1;     // [NB_H][N_NODES]  = 12.8 MB
    u32* part_dst = (u32*)g;      // [NB_H][N_NODES]  = 12.8 MB

    hist_part_kernel<<<NB_H, NT_H, 0, stream>>>(src, part_src);
    reduce_nout_kernel<<<SCAN_NB, 256, 0, stream>>>(part_src, norm_out);

    hist_part_kernel<<<NB_H, NT_H, 0, stream>>>(dst, part_dst);
    colscan_kernel<<<SCAN_NB, 256, 0, stream>>>(part_dst, cnt_in, norm_in);

    scan1_kernel<<<SCAN_NB, 256, 0, stream>>>(cnt_in, start, blocksum);
    scan2_kernel<<<1, 256, 0, stream>>>(blocksum);
    scan3_kernel<<<SCAN_NB, 256, 0, stream>>>(start, blocksum);

    scatter2_kernel<<<NB_H, NT_H, 0, stream>>>(src, dst, start, part_dst, ssrc);
    padw2_kernel<<<(D_H * D_OP + 255) / 256, 256, 0, stream>>>(W2, W2p);

    gemm1_kernel<<<(N_NODES + 63) / 64, 256, 0, stream>>>(feat, W1, norm_out, h1);
    agg1_kernel<<<1024, 256, 0, stream>>>(start, ssrc, h1, norm_in, norm_out, b1, g);

    gemm2_kernel<<<(N_NODES + 63) / 64, 256, 0, stream>>>(g, W2p, h2);
    agg2_kernel<<<1024, 256, 0, stream>>>(start, ssrc, h2, norm_in, b2, out);
}

// Round 6
// 233.595 us; speedup vs baseline: 1.1664x; 1.1664x over previous
//
#include <hip/hip_runtime.h>
#include <stdint.h>

#define N_NODES 50000
#define N_EDGES 800000
#define D_IN    256
#define D_H     64
#define D_O     40
#define D_OP    48   // h2 padded row stride

// CSR build geometry: 256 blocks x 3125-edge slices; node space covered in
// 4 LDS passes of 12500 bins (50 KB LDS, no global atomics). Partial counts
// stored u16 (slice count <= 3125; column prefix bounded by node in-degree,
// ~<=60 for this random-uniform graph).
#define NB_H  256
#define NT_H  512
#define EPB   (N_EDGES / NB_H)    // 3125
#define BINS  12500
#define NPASS 4

typedef unsigned int u32;
typedef unsigned short u16;

// ---------------- per-block partial histogram (LDS atomics only) ----------------

__global__ void __launch_bounds__(NT_H) hist_part_kernel(const int* __restrict__ idx,
                                                         u16* __restrict__ part) {
    __shared__ u32 bins[BINS];
    const int b = blockIdx.x;
    const int e0 = b * EPB;
    const int e1 = (e0 + EPB < N_EDGES) ? e0 + EPB : N_EDGES;
    for (int pass = 0; pass < NPASS; ++pass) {
        const int base = pass * BINS;
        for (int i = threadIdx.x; i < BINS; i += NT_H) bins[i] = 0;
        __syncthreads();
        for (int e = e0 + threadIdx.x; e < e1; e += NT_H) {
            int v = idx[e] - base;
            if ((u32)v < (u32)BINS) atomicAdd(&bins[v], 1u);
        }
        __syncthreads();
        for (int i = threadIdx.x; i < BINS; i += NT_H)
            part[(size_t)b * N_NODES + base + i] = (u16)bins[i];
        __syncthreads();
    }
}

// ---------------- norm_out = rsqrt(max(col-sum of src partials, 1)) ----------------

__global__ void reduce_nout_kernel(const u16* __restrict__ part, float* __restrict__ norm_out) {
    int n = blockIdx.x * blockDim.x + threadIdx.x;
    if (n < N_NODES) {
        u32 acc = 0;
#pragma unroll 8
        for (int b = 0; b < NB_H; ++b) acc += part[(size_t)b * N_NODES + n];
        norm_out[n] = rsqrtf(fmaxf((float)acc, 1.0f));
    }
}

// ---------------- exclusive column-prefix of dst partials (-> off), cnt_in, norm_in ----------------

__global__ void colscan_kernel(u16* __restrict__ part, int* __restrict__ cnt_in,
                               float* __restrict__ norm_in) {
    int n = blockIdx.x * blockDim.x + threadIdx.x;
    if (n < N_NODES) {
        u32 acc = 0;
#pragma unroll 8
        for (int b = 0; b < NB_H; ++b) {
            size_t i = (size_t)b * N_NODES + n;
            u32 t = part[i];
            part[i] = (u16)acc;
            acc += t;
        }
        cnt_in[n] = (int)acc;
        norm_in[n] = rsqrtf(fmaxf((float)acc, 1.0f));
    }
}

// ---------------- exclusive scan of cnt_in -> start[] ----------------

#define SCAN_NB ((N_NODES + 255) / 256)   // 196

__global__ void scan1_kernel(const int* __restrict__ cnt, int* __restrict__ start,
                             int* __restrict__ blocksum) {
    __shared__ int tmp[256];
    int i = blockIdx.x * 256 + threadIdx.x;
    int v = (i < N_NODES) ? cnt[i] : 0;
    tmp[threadIdx.x] = v;
    __syncthreads();
    for (int off = 1; off < 256; off <<= 1) {
        int t = (threadIdx.x >= off) ? tmp[threadIdx.x - off] : 0;
        __syncthreads();
        tmp[threadIdx.x] += t;
        __syncthreads();
    }
    if (i < N_NODES) start[i] = tmp[threadIdx.x] - v;
    if (threadIdx.x == 255) blocksum[blockIdx.x] = tmp[255];
}

__global__ void scan2_kernel(int* __restrict__ blocksum) {
    __shared__ int tmp[256];
    int v = (threadIdx.x < SCAN_NB) ? blocksum[threadIdx.x] : 0;
    tmp[threadIdx.x] = v;
    __syncthreads();
    for (int off = 1; off < 256; off <<= 1) {
        int t = (threadIdx.x >= off) ? tmp[threadIdx.x - off] : 0;
        __syncthreads();
        tmp[threadIdx.x] += t;
        __syncthreads();
    }
    blocksum[threadIdx.x] = tmp[threadIdx.x] - v;
}

__global__ void scan3_kernel(int* __restrict__ start, const int* __restrict__ blocksum) {
    int i = blockIdx.x * 256 + threadIdx.x;
    if (i < N_NODES) start[i] += blocksum[i >> 8];
    if (i == 0) start[N_NODES] = N_EDGES;
}

// ---------------- scatter edges into CSR order (LDS cursors, no global atomics) ----------------

__global__ void __launch_bounds__(NT_H) scatter2_kernel(const int* __restrict__ src,
                                                        const int* __restrict__ dst,
                                                        const int* __restrict__ start,
                                                        const u16* __restrict__ off,
                                                        int* __restrict__ ssrc) {
    __shared__ u32 cur[BINS];
    const int b = blockIdx.x;
    const int e0 = b * EPB;
    const int e1 = (e0 + EPB < N_EDGES) ? e0 + EPB : N_EDGES;
    for (int pass = 0; pass < NPASS; ++pass) {
        const int base = pass * BINS;
        for (int i = threadIdx.x; i < BINS; i += NT_H) cur[i] = 0;
        __syncthreads();
        for (int e = e0 + threadIdx.x; e < e1; e += NT_H) {
            int d = dst[e];
            int r = d - base;
            if ((u32)r < (u32)BINS) {
                u32 c = atomicAdd(&cur[r], 1u);
                int pos = start[d] + (int)off[(size_t)b * N_NODES + d] + (int)c;
                ssrc[pos] = src[e];
            }
        }
        __syncthreads();
    }
}

// ---------------- W2 zero-padded to [64][48] ----------------

__global__ void padw2_kernel(const float* __restrict__ W2, float* __restrict__ W2p) {
    int i = blockIdx.x * blockDim.x + threadIdx.x;
    if (i < D_H * D_OP) {
        int k = i / D_OP, j = i - k * D_OP;
        W2p[i] = (j < D_O) ? W2[k * D_O + j] : 0.0f;
    }
}

// ---------------- GEMM1: h1[n][j] = norm_out[n] * dot(feat[n,:], W1[:,j]) ----------------

#define G1S 33

__global__ void __launch_bounds__(256, 8) gemm1_kernel(const float* __restrict__ feat,
                                                       const float* __restrict__ W1,
                                                       const float* __restrict__ norm_out,
                                                       float* __restrict__ h1) {
    __shared__ float tile[64 * G1S];
    const int tid = threadIdx.x;
    const int lane = tid & 63;
    const int cbase = __builtin_amdgcn_readfirstlane((tid >> 6) * 16);
    const int n0 = blockIdx.x * 64;

    float acc[16];
#pragma unroll
    for (int c = 0; c < 16; ++c) acc[c] = 0.0f;

    for (int k0 = 0; k0 < D_IN; k0 += 32) {
        __syncthreads();
#pragma unroll
        for (int it = 0; it < 2; ++it) {
            int idx = it * 256 + tid;
            int row = idx >> 3;
            int q = idx & 7;
            int nr = n0 + row; if (nr >= N_NODES) nr = N_NODES - 1;
            float4 v = *(const float4*)(feat + nr * D_IN + k0 + q * 4);
            float* dp = &tile[row * G1S + q * 4];
            dp[0] = v.x; dp[1] = v.y; dp[2] = v.z; dp[3] = v.w;
        }
        __syncthreads();
        const float* wp = W1 + k0 * D_H + cbase;
#pragma unroll
        for (int kk = 0; kk < 32; ++kk) {
            float f = tile[lane * G1S + kk];
#pragma unroll
            for (int c = 0; c < 16; ++c)
                acc[c] = fmaf(f, wp[kk * D_H + c], acc[c]);
        }
    }
    int n = n0 + lane;
    if (n < N_NODES) {
        float no = norm_out[n];
        float* hp = h1 + n * D_H + cbase;
#pragma unroll
        for (int c0 = 0; c0 < 16; c0 += 4) {
            float4 r = make_float4(acc[c0] * no, acc[c0 + 1] * no,
                                   acc[c0 + 2] * no, acc[c0 + 3] * no);
            *(float4*)(hp + c0) = r;
        }
    }
}

// ---------------- agg1: g[n][:] = relu(sum_e h1[ssrc[e]][:] * ni + b1) * no ----------------

__global__ void __launch_bounds__(256) agg1_kernel(const int* __restrict__ start,
                                                   const int* __restrict__ ssrc,
                                                   const float* __restrict__ h1,
                                                   const float* __restrict__ norm_in,
                                                   const float* __restrict__ norm_out,
                                                   const float* __restrict__ b1,
                                                   float* __restrict__ g) {
    const int lane = threadIdx.x & 63;
    const int q = lane & 15;
    const int t = lane >> 4;
    const int wave = (int)((blockIdx.x * blockDim.x + threadIdx.x) >> 6);
    const int nwaves = (int)((gridDim.x * blockDim.x) >> 6);

    const float4 bq = *(const float4*)&b1[q * 4];

    for (int n = wave; n < N_NODES; n += nwaves) {
        int beg = __builtin_amdgcn_readfirstlane(start[n]);
        int end = __builtin_amdgcn_readfirstlane(start[n + 1]);
        float4 acc = make_float4(0.f, 0.f, 0.f, 0.f);
        for (int e = beg + t; e < end; e += 4) {
            int s = ssrc[e];
            float4 v = *(const float4*)(h1 + s * D_H + q * 4);
            acc.x += v.x; acc.y += v.y; acc.z += v.z; acc.w += v.w;
        }
        acc.x += __shfl_xor(acc.x, 16); acc.y += __shfl_xor(acc.y, 16);
        acc.z += __shfl_xor(acc.z, 16); acc.w += __shfl_xor(acc.w, 16);
        acc.x += __shfl_xor(acc.x, 32); acc.y += __shfl_xor(acc.y, 32);
        acc.z += __shfl_xor(acc.z, 32); acc.w += __shfl_xor(acc.w, 32);
        if (t == 0) {
            float ni = norm_in[n], no = norm_out[n];
            float4 r;
            r.x = fmaxf(fmaf(acc.x, ni, bq.x), 0.f) * no;
            r.y = fmaxf(fmaf(acc.y, ni, bq.y), 0.f) * no;
            r.z = fmaxf(fmaf(acc.z, ni, bq.z), 0.f) * no;
            r.w = fmaxf(fmaf(acc.w, ni, bq.w), 0.f) * no;
            *(float4*)(g + n * D_H + q * 4) = r;
        }
    }
}

// ---------------- GEMM2: h2[n][0:48] = dot(g[n,:64], W2p[:,0:48]) ----------------

__global__ void __launch_bounds__(256, 8) gemm2_kernel(const float* __restrict__ g,
                                                       const float* __restrict__ W2p,
                                                       float* __restrict__ h2) {
    __shared__ float tile[64 * G1S];
    const int tid = threadIdx.x;
    const int lane = tid & 63;
    const int cbase = __builtin_amdgcn_readfirstlane((tid >> 6) * 12);
    const int n0 = blockIdx.x * 64;

    float acc[12];
#pragma unroll
    for (int c = 0; c < 12; ++c) acc[c] = 0.0f;

    for (int k0 = 0; k0 < D_H; k0 += 32) {
        __syncthreads();
#pragma unroll
        for (int it = 0; it < 2; ++it) {
            int idx = it * 256 + tid;
            int row = idx >> 3;
            int q = idx & 7;
            int nr = n0 + row; if (nr >= N_NODES) nr = N_NODES - 1;
            float4 v = *(const float4*)(g + nr * D_H + k0 + q * 4);
            float* dp = &tile[row * G1S + q * 4];
            dp[0] = v.x; dp[1] = v.y; dp[2] = v.z; dp[3] = v.w;
        }
        __syncthreads();
        const float* wp = W2p + k0 * D_OP + cbase;
#pragma unroll
        for (int kk = 0; kk < 32; ++kk) {
            float f = tile[lane * G1S + kk];
#pragma unroll
            for (int c = 0; c < 12; ++c)
                acc[c] = fmaf(f, wp[kk * D_OP + c], acc[c]);
        }
    }
    int n = n0 + lane;
    if (n < N_NODES) {
        float* hp = h2 + n * D_OP + cbase;
#pragma unroll
        for (int c0 = 0; c0 < 12; c0 += 4) {
            float4 r = make_float4(acc[c0], acc[c0 + 1], acc[c0 + 2], acc[c0 + 3]);
            *(float4*)(hp + c0) = r;
        }
    }
}

// ---------------- agg2: out[n][:] = (sum_e h2[ssrc[e]][:]) * ni + b2 ----------------

__global__ void __launch_bounds__(256) agg2_kernel(const int* __restrict__ start,
                                                   const int* __restrict__ ssrc,
                                                   const float* __restrict__ h2,
                                                   const float* __restrict__ norm_in,
                                                   const float* __restrict__ b2,
                                                   float* __restrict__ out) {
    const int lane = threadIdx.x & 63;
    const int q = lane % 12;
    const int t = lane / 12;           // 0..5; t==5 idle
    const int wave = (int)((blockIdx.x * blockDim.x + threadIdx.x) >> 6);
    const int nwaves = (int)((gridDim.x * blockDim.x) >> 6);

    for (int n = wave; n < N_NODES; n += nwaves) {
        int beg = __builtin_amdgcn_readfirstlane(start[n]);
        int end = __builtin_amdgcn_readfirstlane(start[n + 1]);
        float4 acc = make_float4(0.f, 0.f, 0.f, 0.f);
        if (t < 5) {
            for (int e = beg + t; e < end; e += 5) {
                int s = ssrc[e];
                float4 v = *(const float4*)(h2 + s * D_OP + q * 4);
                acc.x += v.x; acc.y += v.y; acc.z += v.z; acc.w += v.w;
            }
        }
        float sx = acc.x, sy = acc.y, sz = acc.z, sw = acc.w;
#pragma unroll
        for (int o = 1; o < 5; ++o) {
            sx += __shfl(acc.x, lane + o * 12, 64);
            sy += __shfl(acc.y, lane + o * 12, 64);
            sz += __shfl(acc.z, lane + o * 12, 64);
            sw += __shfl(acc.w, lane + o * 12, 64);
        }
        if (lane < 10) {
            float ni = norm_in[n];
            float4 bq = *(const float4*)&b2[lane * 4];
            float4 r;
            r.x = fmaf(sx, ni, bq.x);
            r.y = fmaf(sy, ni, bq.y);
            r.z = fmaf(sz, ni, bq.z);
            r.w = fmaf(sw, ni, bq.w);
            *(float4*)(out + (size_t)n * D_O + lane * 4) = r;
        }
    }
}

// ----------------------------------------------------------------------------

static inline char* alignup(char* p, size_t a) {
    return (char*)(((uintptr_t)p + a - 1) & ~(uintptr_t)(a - 1));
}

extern "C" void kernel_launch(void* const* d_in, const int* in_sizes, int n_in,
                              void* d_out, int out_size, void* d_ws, size_t ws_size,
                              hipStream_t stream) {
    const float* feat = (const float*)d_in[0];
    const int*   src  = (const int*)d_in[1];
    const int*   dst  = (const int*)d_in[2];
    const float* W1   = (const float*)d_in[3];
    const float* b1   = (const float*)d_in[4];
    const float* W2   = (const float*)d_in[5];
    const float* b2   = (const float*)d_in[6];
    float* out = (float*)d_out;

    char* p = alignup((char*)d_ws, 256);
    int*   cnt_in   = (int*)p;    p = alignup(p + N_NODES * 4, 256);
    int*   start    = (int*)p;    p = alignup(p + (N_NODES + 1) * 4, 256);
    int*   blocksum = (int*)p;    p = alignup(p + 256 * 4, 256);
    float* norm_out = (float*)p;  p = alignup(p + N_NODES * 4, 256);
    float* norm_in  = (float*)p;  p = alignup(p + N_NODES * 4, 256);
    float* W2p      = (float*)p;  p = alignup(p + D_H * D_OP * 4, 256);
    int*   ssrc     = (int*)p;    p = alignup(p + N_EDGES * 4, 256);
    float* h1       = (float*)p;  p = alignup(p + (size_t)N_NODES * D_H * 4, 256);
    float* g        = (float*)p;  p = alignup(p + (size_t)N_NODES * D_H * 4, 256);
    float* h2       = h1;         // h1 dead after agg1

    // u16 partial-count matrix [NB_H][N_NODES] = 25.6 MB, aliasing h1+g
    // (h1 is 12.8 MB, g follows contiguously). Used twice, sequentially:
    // src partials (dead after reduce_nout, before gemm1 writes h1) then
    // dst partials (dead after scatter2, before agg1 writes g).
    u16* part = (u16*)h1;

    hist_part_kernel<<<NB_H, NT_H, 0, stream>>>(src, part);
    reduce_nout_kernel<<<SCAN_NB, 256, 0, stream>>>(part, norm_out);

    hist_part_kernel<<<NB_H, NT_H, 0, stream>>>(dst, part);
    colscan_kernel<<<SCAN_NB, 256, 0, stream>>>(part, cnt_in, norm_in);

    scan1_kernel<<<SCAN_NB, 256, 0, stream>>>(cnt_in, start, blocksum);
    scan2_kernel<<<1, 256, 0, stream>>>(blocksum);
    scan3_kernel<<<SCAN_NB, 256, 0, stream>>>(start, blocksum);

    scatter2_kernel<<<NB_H, NT_H, 0, stream>>>(src, dst, start, part, ssrc);
    padw2_kernel<<<(D_H * D_OP + 255) / 256, 256, 0, stream>>>(W2, W2p);

    gemm1_kernel<<<(N_NODES + 63) / 64, 256, 0, stream>>>(feat, W1, norm_out, h1);
    agg1_kernel<<<1024, 256, 0, stream>>>(start, ssrc, h1, norm_in, norm_out, b1, g);

    gemm2_kernel<<<(N_NODES + 63) / 64, 256, 0, stream>>>(g, W2p, h2);
    agg2_kernel<<<1024, 256, 0, stream>>>(start, ssrc, h2, norm_in, b2, out);
}

// Round 7
// 196.054 us; speedup vs baseline: 1.3898x; 1.1915x over previous
//
#include <hip/hip_runtime.h>
#include <stdint.h>

#define N_NODES 50000
#define N_EDGES 800000
#define D_IN    256
#define D_H     64
#define D_O     40
#define D_OP    48   // h2 padded row stride

// CSR build geometry: 256 blocks x 3125-edge slices; node space covered in
// 4 LDS passes of 12500 bins (50 KB LDS, no global atomics). Partial counts
// stored u16.
#define NB_H  256
#define NT_H  512
#define EPB   (N_EDGES / NB_H)    // 3125
#define BINS  12500
#define NPASS 4

typedef unsigned int u32;
typedef unsigned short u16;

// ---------------- per-block partial histogram (LDS atomics only) ----------------

__global__ void __launch_bounds__(NT_H) hist_part_kernel(const int* __restrict__ idx,
                                                         u16* __restrict__ part) {
    __shared__ u32 bins[BINS];
    const int b = blockIdx.x;
    const int e0 = b * EPB;
    const int e1 = (e0 + EPB < N_EDGES) ? e0 + EPB : N_EDGES;
    for (int pass = 0; pass < NPASS; ++pass) {
        const int base = pass * BINS;
        for (int i = threadIdx.x; i < BINS; i += NT_H) bins[i] = 0;
        __syncthreads();
        for (int e = e0 + threadIdx.x; e < e1; e += NT_H) {
            int v = idx[e] - base;
            if ((u32)v < (u32)BINS) atomicAdd(&bins[v], 1u);
        }
        __syncthreads();
        for (int i = threadIdx.x; i < BINS; i += NT_H)
            part[(size_t)b * N_NODES + base + i] = (u16)bins[i];
        __syncthreads();
    }
}

// ---------------- norm_out = rsqrt(max(col-sum of src partials, 1)) ----------------

__global__ void reduce_nout_kernel(const u16* __restrict__ part, float* __restrict__ norm_out) {
    int n = blockIdx.x * blockDim.x + threadIdx.x;
    if (n < N_NODES) {
        u32 acc = 0;
#pragma unroll 8
        for (int b = 0; b < NB_H; ++b) acc += part[(size_t)b * N_NODES + n];
        norm_out[n] = rsqrtf(fmaxf((float)acc, 1.0f));
    }
}

// ---------------- exclusive column-prefix of dst partials (-> off), cnt_in, norm_in ----------------

__global__ void colscan_kernel(u16* __restrict__ part, int* __restrict__ cnt_in,
                               float* __restrict__ norm_in) {
    int n = blockIdx.x * blockDim.x + threadIdx.x;
    if (n < N_NODES) {
        u32 acc = 0;
#pragma unroll 8
        for (int b = 0; b < NB_H; ++b) {
            size_t i = (size_t)b * N_NODES + n;
            u32 t = part[i];
            part[i] = (u16)acc;
            acc += t;
        }
        cnt_in[n] = (int)acc;
        norm_in[n] = rsqrtf(fmaxf((float)acc, 1.0f));
    }
}

// ---------------- exclusive scan of cnt_in -> start[] ----------------

#define SCAN_NB ((N_NODES + 255) / 256)   // 196

__global__ void scan1_kernel(const int* __restrict__ cnt, int* __restrict__ start,
                             int* __restrict__ blocksum) {
    __shared__ int tmp[256];
    int i = blockIdx.x * 256 + threadIdx.x;
    int v = (i < N_NODES) ? cnt[i] : 0;
    tmp[threadIdx.x] = v;
    __syncthreads();
    for (int off = 1; off < 256; off <<= 1) {
        int t = (threadIdx.x >= off) ? tmp[threadIdx.x - off] : 0;
        __syncthreads();
        tmp[threadIdx.x] += t;
        __syncthreads();
    }
    if (i < N_NODES) start[i] = tmp[threadIdx.x] - v;
    if (threadIdx.x == 255) blocksum[blockIdx.x] = tmp[255];
}

__global__ void scan2_kernel(int* __restrict__ blocksum) {
    __shared__ int tmp[256];
    int v = (threadIdx.x < SCAN_NB) ? blocksum[threadIdx.x] : 0;
    tmp[threadIdx.x] = v;
    __syncthreads();
    for (int off = 1; off < 256; off <<= 1) {
        int t = (threadIdx.x >= off) ? tmp[threadIdx.x - off] : 0;
        __syncthreads();
        tmp[threadIdx.x] += t;
        __syncthreads();
    }
    blocksum[threadIdx.x] = tmp[threadIdx.x] - v;
}

__global__ void scan3_kernel(int* __restrict__ start, const int* __restrict__ blocksum) {
    int i = blockIdx.x * 256 + threadIdx.x;
    if (i < N_NODES) start[i] += blocksum[i >> 8];
    if (i == 0) start[N_NODES] = N_EDGES;
}

// ---------------- scatter edges into CSR order (LDS cursors, no global atomics) ----------------

__global__ void __launch_bounds__(NT_H) scatter2_kernel(const int* __restrict__ src,
                                                        const int* __restrict__ dst,
                                                        const int* __restrict__ start,
                                                        const u16* __restrict__ off,
                                                        int* __restrict__ ssrc) {
    __shared__ u32 cur[BINS];
    const int b = blockIdx.x;
    const int e0 = b * EPB;
    const int e1 = (e0 + EPB < N_EDGES) ? e0 + EPB : N_EDGES;
    for (int pass = 0; pass < NPASS; ++pass) {
        const int base = pass * BINS;
        for (int i = threadIdx.x; i < BINS; i += NT_H) cur[i] = 0;
        __syncthreads();
        for (int e = e0 + threadIdx.x; e < e1; e += NT_H) {
            int d = dst[e];
            int r = d - base;
            if ((u32)r < (u32)BINS) {
                u32 c = atomicAdd(&cur[r], 1u);
                int pos = start[d] + (int)off[(size_t)b * N_NODES + d] + (int)c;
                ssrc[pos] = src[e];
            }
        }
        __syncthreads();
    }
}

// ---------------- W2 zero-padded to [64][48] ----------------

__global__ void padw2_kernel(const float* __restrict__ W2, float* __restrict__ W2p) {
    int i = blockIdx.x * blockDim.x + threadIdx.x;
    if (i < D_H * D_OP) {
        int k = i / D_OP, j = i - k * D_OP;
        W2p[i] = (j < D_O) ? W2[k * D_O + j] : 0.0f;
    }
}

// ---------------- GEMM1: h1[n][j] = norm_out[n] * dot(feat[n,:], W1[:,j]) ----------------
// 512 thr = 8 waves: (wave&3) = 16-col group, (wave>>2) = K-half.
// Per K-chunk of 32: each wave handles 16 kk x 16 cols; W via wave-uniform
// scalar loads. Two K-halves combined through LDS at the end.

#define G1S 33

__global__ void __launch_bounds__(512, 8) gemm1_kernel(const float* __restrict__ feat,
                                                       const float* __restrict__ W1,
                                                       const float* __restrict__ norm_out,
                                                       float* __restrict__ h1) {
    __shared__ float tile[64 * G1S];        // 8448 B
    __shared__ float part[4][16][64];       // 16384 B, [colgrp][c][row]
    const int tid = threadIdx.x;
    const int lane = tid & 63;
    const int wq = __builtin_amdgcn_readfirstlane((tid >> 6) & 3);
    const int kh = __builtin_amdgcn_readfirstlane(tid >> 8);   // 0 or 1
    const int cbase = wq * 16;
    const int n0 = blockIdx.x * 64;

    float acc[16];
#pragma unroll
    for (int c = 0; c < 16; ++c) acc[c] = 0.0f;

    for (int k0 = 0; k0 < D_IN; k0 += 32) {
        __syncthreads();
        {
            int row = tid >> 3;             // 0..63
            int q = tid & 7;                // 0..7
            int nr = n0 + row; if (nr >= N_NODES) nr = N_NODES - 1;
            float4 v = *(const float4*)(feat + nr * D_IN + k0 + q * 4);
            float* dp = &tile[row * G1S + q * 4];
            dp[0] = v.x; dp[1] = v.y; dp[2] = v.z; dp[3] = v.w;
        }
        __syncthreads();
        const float* wp = W1 + (k0 + kh * 16) * D_H + cbase;   // wave-uniform
#pragma unroll
        for (int kk = 0; kk < 16; ++kk) {
            float f = tile[lane * G1S + kh * 16 + kk];
#pragma unroll
            for (int c = 0; c < 16; ++c)
                acc[c] = fmaf(f, wp[kk * D_H + c], acc[c]);
        }
    }
    // combine the two K-halves
    if (kh == 1) {
#pragma unroll
        for (int c = 0; c < 16; ++c) part[wq][c][lane] = acc[c];
    }
    __syncthreads();
    if (kh == 0) {
        int n = n0 + lane;
        if (n < N_NODES) {
            float no = norm_out[n];
#pragma unroll
            for (int c = 0; c < 16; ++c) acc[c] = (acc[c] + part[wq][c][lane]) * no;
            float* hp = h1 + n * D_H + cbase;
#pragma unroll
            for (int c0 = 0; c0 < 16; c0 += 4)
                *(float4*)(hp + c0) = make_float4(acc[c0], acc[c0 + 1], acc[c0 + 2], acc[c0 + 3]);
        }
    }
}

// ---------------- agg1: g[n][:] = relu(sum_e h1[ssrc[e]][:] * ni + b1) * no ----------------
// ONE wave per node (50000 waves); lane = (dim-quad q, edge slot t).

__global__ void __launch_bounds__(256) agg1_kernel(const int* __restrict__ start,
                                                   const int* __restrict__ ssrc,
                                                   const float* __restrict__ h1,
                                                   const float* __restrict__ norm_in,
                                                   const float* __restrict__ norm_out,
                                                   const float* __restrict__ b1,
                                                   float* __restrict__ g) {
    const int lane = threadIdx.x & 63;
    const int q = lane & 15;
    const int t = lane >> 4;
    const int n = (int)((blockIdx.x * blockDim.x + threadIdx.x) >> 6);
    if (n >= N_NODES) return;

    int beg = __builtin_amdgcn_readfirstlane(start[n]);
    int end = __builtin_amdgcn_readfirstlane(start[n + 1]);
    float4 acc = make_float4(0.f, 0.f, 0.f, 0.f);
    for (int e = beg + t; e < end; e += 4) {
        int s = ssrc[e];
        float4 v = *(const float4*)(h1 + s * D_H + q * 4);
        acc.x += v.x; acc.y += v.y; acc.z += v.z; acc.w += v.w;
    }
    acc.x += __shfl_xor(acc.x, 16); acc.y += __shfl_xor(acc.y, 16);
    acc.z += __shfl_xor(acc.z, 16); acc.w += __shfl_xor(acc.w, 16);
    acc.x += __shfl_xor(acc.x, 32); acc.y += __shfl_xor(acc.y, 32);
    acc.z += __shfl_xor(acc.z, 32); acc.w += __shfl_xor(acc.w, 32);
    if (t == 0) {
        float ni = norm_in[n], no = norm_out[n];
        const float4 bq = *(const float4*)&b1[q * 4];
        float4 r;
        r.x = fmaxf(fmaf(acc.x, ni, bq.x), 0.f) * no;
        r.y = fmaxf(fmaf(acc.y, ni, bq.y), 0.f) * no;
        r.z = fmaxf(fmaf(acc.z, ni, bq.z), 0.f) * no;
        r.w = fmaxf(fmaf(acc.w, ni, bq.w), 0.f) * no;
        *(float4*)(g + n * D_H + q * 4) = r;
    }
}

// ---------------- GEMM2: h2[n][0:48] = dot(g[n,:64], W2p[:,0:48]) ----------------
// 512 thr = 8 waves: (wave&3) = 12-col group, (wave>>2) = K-half (32 each).
// K=64 staged once.

__global__ void __launch_bounds__(512, 8) gemm2_kernel(const float* __restrict__ g,
                                                       const float* __restrict__ W2p,
                                                       float* __restrict__ h2) {
    __shared__ float tile[64 * 65];         // 16640 B
    __shared__ float part[4][12][64];       // 12288 B
    const int tid = threadIdx.x;
    const int lane = tid & 63;
    const int wq = __builtin_amdgcn_readfirstlane((tid >> 6) & 3);
    const int kh = __builtin_amdgcn_readfirstlane(tid >> 8);
    const int cbase = wq * 12;
    const int n0 = blockIdx.x * 64;

    // stage 64x64 block of g
#pragma unroll
    for (int it = 0; it < 2; ++it) {
        int idx = it * 512 + tid;           // 0..1023
        int row = idx >> 4;                 // 0..63
        int q = idx & 15;                   // 0..15
        int nr = n0 + row; if (nr >= N_NODES) nr = N_NODES - 1;
        float4 v = *(const float4*)(g + nr * D_H + q * 4);
        float* dp = &tile[row * 65 + q * 4];
        dp[0] = v.x; dp[1] = v.y; dp[2] = v.z; dp[3] = v.w;
    }
    __syncthreads();

    float acc[12];
#pragma unroll
    for (int c = 0; c < 12; ++c) acc[c] = 0.0f;

    const float* wp = W2p + kh * 32 * D_OP + cbase;   // wave-uniform
#pragma unroll
    for (int kk = 0; kk < 32; ++kk) {
        float f = tile[lane * 65 + kh * 32 + kk];
#pragma unroll
        for (int c = 0; c < 12; ++c)
            acc[c] = fmaf(f, wp[kk * D_OP + c], acc[c]);
    }

    if (kh == 1) {
#pragma unroll
        for (int c = 0; c < 12; ++c) part[wq][c][lane] = acc[c];
    }
    __syncthreads();
    if (kh == 0) {
        int n = n0 + lane;
        if (n < N_NODES) {
#pragma unroll
            for (int c = 0; c < 12; ++c) acc[c] += part[wq][c][lane];
            float* hp = h2 + n * D_OP + cbase;
#pragma unroll
            for (int c0 = 0; c0 < 12; c0 += 4)
                *(float4*)(hp + c0) = make_float4(acc[c0], acc[c0 + 1], acc[c0 + 2], acc[c0 + 3]);
        }
    }
}

// ---------------- agg2: out[n][:] = (sum_e h2[ssrc[e]][:]) * ni + b2 ----------------
// ONE wave per node.

__global__ void __launch_bounds__(256) agg2_kernel(const int* __restrict__ start,
                                                   const int* __restrict__ ssrc,
                                                   const float* __restrict__ h2,
                                                   const float* __restrict__ norm_in,
                                                   const float* __restrict__ b2,
                                                   float* __restrict__ out) {
    const int lane = threadIdx.x & 63;
    const int q = lane % 12;
    const int t = lane / 12;           // 0..5; t==5 idle
    const int n = (int)((blockIdx.x * blockDim.x + threadIdx.x) >> 6);
    if (n >= N_NODES) return;

    int beg = __builtin_amdgcn_readfirstlane(start[n]);
    int end = __builtin_amdgcn_readfirstlane(start[n + 1]);
    float4 acc = make_float4(0.f, 0.f, 0.f, 0.f);
    if (t < 5) {
        for (int e = beg + t; e < end; e += 5) {
            int s = ssrc[e];
            float4 v = *(const float4*)(h2 + s * D_OP + q * 4);
            acc.x += v.x; acc.y += v.y; acc.z += v.z; acc.w += v.w;
        }
    }
    float sx = acc.x, sy = acc.y, sz = acc.z, sw = acc.w;
#pragma unroll
    for (int o = 1; o < 5; ++o) {
        sx += __shfl(acc.x, lane + o * 12, 64);
        sy += __shfl(acc.y, lane + o * 12, 64);
        sz += __shfl(acc.z, lane + o * 12, 64);
        sw += __shfl(acc.w, lane + o * 12, 64);
    }
    if (lane < 10) {
        float ni = norm_in[n];
        float4 bq = *(const float4*)&b2[lane * 4];
        float4 r;
        r.x = fmaf(sx, ni, bq.x);
        r.y = fmaf(sy, ni, bq.y);
        r.z = fmaf(sz, ni, bq.z);
        r.w = fmaf(sw, ni, bq.w);
        *(float4*)(out + (size_t)n * D_O + lane * 4) = r;
    }
}

// ----------------------------------------------------------------------------

static inline char* alignup(char* p, size_t a) {
    return (char*)(((uintptr_t)p + a - 1) & ~(uintptr_t)(a - 1));
}

extern "C" void kernel_launch(void* const* d_in, const int* in_sizes, int n_in,
                              void* d_out, int out_size, void* d_ws, size_t ws_size,
                              hipStream_t stream) {
    const float* feat = (const float*)d_in[0];
    const int*   src  = (const int*)d_in[1];
    const int*   dst  = (const int*)d_in[2];
    const float* W1   = (const float*)d_in[3];
    const float* b1   = (const float*)d_in[4];
    const float* W2   = (const float*)d_in[5];
    const float* b2   = (const float*)d_in[6];
    float* out = (float*)d_out;

    char* p = alignup((char*)d_ws, 256);
    int*   cnt_in   = (int*)p;    p = alignup(p + N_NODES * 4, 256);
    int*   start    = (int*)p;    p = alignup(p + (N_NODES + 1) * 4, 256);
    int*   blocksum = (int*)p;    p = alignup(p + 256 * 4, 256);
    float* norm_out = (float*)p;  p = alignup(p + N_NODES * 4, 256);
    float* norm_in  = (float*)p;  p = alignup(p + N_NODES * 4, 256);
    float* W2p      = (float*)p;  p = alignup(p + D_H * D_OP * 4, 256);
    int*   ssrc     = (int*)p;    p = alignup(p + N_EDGES * 4, 256);
    float* h1       = (float*)p;  p = alignup(p + (size_t)N_NODES * D_H * 4, 256);
    float* g        = (float*)p;  p = alignup(p + (size_t)N_NODES * D_H * 4, 256);
    float* h2       = h1;         // h1 dead after agg1

    // u16 partial-count matrix [NB_H][N_NODES] = 25.6 MB, aliasing h1+g.
    u16* part = (u16*)h1;

    hist_part_kernel<<<NB_H, NT_H, 0, stream>>>(src, part);
    reduce_nout_kernel<<<SCAN_NB, 256, 0, stream>>>(part, norm_out);

    hist_part_kernel<<<NB_H, NT_H, 0, stream>>>(dst, part);
    colscan_kernel<<<SCAN_NB, 256, 0, stream>>>(part, cnt_in, norm_in);

    scan1_kernel<<<SCAN_NB, 256, 0, stream>>>(cnt_in, start, blocksum);
    scan2_kernel<<<1, 256, 0, stream>>>(blocksum);
    scan3_kernel<<<SCAN_NB, 256, 0, stream>>>(start, blocksum);

    scatter2_kernel<<<NB_H, NT_H, 0, stream>>>(src, dst, start, part, ssrc);
    padw2_kernel<<<(D_H * D_OP + 255) / 256, 256, 0, stream>>>(W2, W2p);

    gemm1_kernel<<<(N_NODES + 63) / 64, 512, 0, stream>>>(feat, W1, norm_out, h1);
    agg1_kernel<<<(N_NODES + 3) / 4, 256, 0, stream>>>(start, ssrc, h1, norm_in, norm_out, b1, g);

    gemm2_kernel<<<(N_NODES + 63) / 64, 512, 0, stream>>>(g, W2p, h2);
    agg2_kernel<<<(N_NODES + 3) / 4, 256, 0, stream>>>(start, ssrc, h2, norm_in, b2, out);
}

// Round 8
// 191.986 us; speedup vs baseline: 1.4192x; 1.0212x over previous
//
#include <hip/hip_runtime.h>
#include <stdint.h>

#define N_NODES 50000
#define N_EDGES 800000
#define D_IN    256
#define D_H     64
#define D_O     40
#define D_OP    48   // h2 padded row stride

// CSR build geometry: 256 blocks x 3125-edge slices; node space covered in
// 2 LDS passes of 25000 nodes packed 2-per-u32 (50 KB LDS, no global atomics).
// Counts fit u16 (slice count <= 3125).
#define NB_H   256
#define NT_H   512
#define EPB    (N_EDGES / NB_H)   // 3125
#define BINS_N 25000              // nodes per pass
#define BINS_W 12500              // u32 words (2 nodes each)
#define NPASS  2

typedef unsigned int u32;
typedef unsigned short u16;

// ---------------- per-block partial histogram (packed LDS atomics) ----------------

__global__ void __launch_bounds__(NT_H) hist_part_kernel(const int* __restrict__ idx,
                                                         u16* __restrict__ part) {
    __shared__ u32 bins[BINS_W];
    const int b = blockIdx.x;
    const int e0 = b * EPB;
    const int e1 = (e0 + EPB < N_EDGES) ? e0 + EPB : N_EDGES;
    for (int pass = 0; pass < NPASS; ++pass) {
        const int base = pass * BINS_N;
        for (int i = threadIdx.x; i < BINS_W; i += NT_H) bins[i] = 0;
        __syncthreads();
        for (int e = e0 + threadIdx.x; e < e1; e += NT_H) {
            int v = idx[e] - base;
            if ((u32)v < (u32)BINS_N)
                atomicAdd(&bins[v >> 1], (v & 1) ? 0x10000u : 1u);
        }
        __syncthreads();
        for (int i = threadIdx.x; i < BINS_N; i += NT_H) {
            u32 w = bins[i >> 1];
            part[(size_t)b * N_NODES + base + i] = (u16)((i & 1) ? (w >> 16) : (w & 0xFFFFu));
        }
        __syncthreads();
    }
}

// ---------------- norm_out = rsqrt(max(col-sum of src partials, 1)) ----------------

__global__ void reduce_nout_kernel(const u16* __restrict__ part, float* __restrict__ norm_out) {
    int n = blockIdx.x * blockDim.x + threadIdx.x;
    if (n < N_NODES) {
        u32 acc = 0;
#pragma unroll 8
        for (int b = 0; b < NB_H; ++b) acc += part[(size_t)b * N_NODES + n];
        norm_out[n] = rsqrtf(fmaxf((float)acc, 1.0f));
    }
}

// ---------------- exclusive column-prefix of dst partials (-> off), cnt_in, norm_in ----------------

__global__ void colscan_kernel(u16* __restrict__ part, int* __restrict__ cnt_in,
                               float* __restrict__ norm_in) {
    int n = blockIdx.x * blockDim.x + threadIdx.x;
    if (n < N_NODES) {
        u32 acc = 0;
#pragma unroll 8
        for (int b = 0; b < NB_H; ++b) {
            size_t i = (size_t)b * N_NODES + n;
            u32 t = part[i];
            part[i] = (u16)acc;
            acc += t;
        }
        cnt_in[n] = (int)acc;
        norm_in[n] = rsqrtf(fmaxf((float)acc, 1.0f));
    }
}

// ---------------- exclusive scan of cnt_in -> start[] ----------------

#define SCAN_NB ((N_NODES + 255) / 256)   // 196

__global__ void scan1_kernel(const int* __restrict__ cnt, int* __restrict__ start,
                             int* __restrict__ blocksum) {
    __shared__ int tmp[256];
    int i = blockIdx.x * 256 + threadIdx.x;
    int v = (i < N_NODES) ? cnt[i] : 0;
    tmp[threadIdx.x] = v;
    __syncthreads();
    for (int off = 1; off < 256; off <<= 1) {
        int t = (threadIdx.x >= off) ? tmp[threadIdx.x - off] : 0;
        __syncthreads();
        tmp[threadIdx.x] += t;
        __syncthreads();
    }
    if (i < N_NODES) start[i] = tmp[threadIdx.x] - v;
    if (threadIdx.x == 255) blocksum[blockIdx.x] = tmp[255];
}

__global__ void scan2_kernel(int* __restrict__ blocksum) {
    __shared__ int tmp[256];
    int v = (threadIdx.x < SCAN_NB) ? blocksum[threadIdx.x] : 0;
    tmp[threadIdx.x] = v;
    __syncthreads();
    for (int off = 1; off < 256; off <<= 1) {
        int t = (threadIdx.x >= off) ? tmp[threadIdx.x - off] : 0;
        __syncthreads();
        tmp[threadIdx.x] += t;
        __syncthreads();
    }
    blocksum[threadIdx.x] = tmp[threadIdx.x] - v;
}

__global__ void scan3_kernel(int* __restrict__ start, const int* __restrict__ blocksum) {
    int i = blockIdx.x * 256 + threadIdx.x;
    if (i < N_NODES) start[i] += blocksum[i >> 8];
    if (i == 0) start[N_NODES] = N_EDGES;
}

// ---------------- scatter edges into CSR order (packed LDS cursors) ----------------

__global__ void __launch_bounds__(NT_H) scatter2_kernel(const int* __restrict__ src,
                                                        const int* __restrict__ dst,
                                                        const int* __restrict__ start,
                                                        const u16* __restrict__ off,
                                                        int* __restrict__ ssrc) {
    __shared__ u32 cur[BINS_W];
    const int b = blockIdx.x;
    const int e0 = b * EPB;
    const int e1 = (e0 + EPB < N_EDGES) ? e0 + EPB : N_EDGES;
    for (int pass = 0; pass < NPASS; ++pass) {
        const int base = pass * BINS_N;
        for (int i = threadIdx.x; i < BINS_W; i += NT_H) cur[i] = 0;
        __syncthreads();
        for (int e = e0 + threadIdx.x; e < e1; e += NT_H) {
            int d = dst[e];
            int r = d - base;
            if ((u32)r < (u32)BINS_N) {
                u32 old = atomicAdd(&cur[r >> 1], (r & 1) ? 0x10000u : 1u);
                int c = (int)((r & 1) ? (old >> 16) : (old & 0xFFFFu));
                int pos = start[d] + (int)off[(size_t)b * N_NODES + d] + c;
                ssrc[pos] = src[e];
            }
        }
        __syncthreads();
    }
}

// ---------------- W2 zero-padded to [64][48] ----------------

__global__ void padw2_kernel(const float* __restrict__ W2, float* __restrict__ W2p) {
    int i = blockIdx.x * blockDim.x + threadIdx.x;
    if (i < D_H * D_OP) {
        int k = i / D_OP, j = i - k * D_OP;
        W2p[i] = (j < D_O) ? W2[k * D_O + j] : 0.0f;
    }
}

// ---------------- GEMM1: h1[n][j] = norm_out[n] * dot(feat[n,:], W1[:,j]) ----------------
// 512 thr = 8 waves: (wave&3) = 16-col group, (wave>>2) = K-half.
// Per K-chunk of 32: hoist the wave's 16 tile values into f[] VGPRs FIRST
// (ds_reads complete under one wait), then a pure FMA + scalar-W region —
// s_loads are the only lgkmcnt users there, so the compiler can pipeline
// them with counted waits instead of lgkmcnt(0) per 16-FMA block.

#define G1S 33

__global__ void __launch_bounds__(512, 8) gemm1_kernel(const float* __restrict__ feat,
                                                       const float* __restrict__ W1,
                                                       const float* __restrict__ norm_out,
                                                       float* __restrict__ h1) {
    __shared__ float tile[64 * G1S];        // 8448 B
    __shared__ float part[4][16][64];       // 16384 B
    const int tid = threadIdx.x;
    const int lane = tid & 63;
    const int wq = __builtin_amdgcn_readfirstlane((tid >> 6) & 3);
    const int kh = __builtin_amdgcn_readfirstlane(tid >> 8);   // 0 or 1
    const int cbase = wq * 16;
    const int n0 = blockIdx.x * 64;

    float acc[16];
#pragma unroll
    for (int c = 0; c < 16; ++c) acc[c] = 0.0f;

    for (int k0 = 0; k0 < D_IN; k0 += 32) {
        __syncthreads();
        {
            int row = tid >> 3;             // 0..63
            int q = tid & 7;                // 0..7
            int nr = n0 + row; if (nr >= N_NODES) nr = N_NODES - 1;
            float4 v = *(const float4*)(feat + nr * D_IN + k0 + q * 4);
            float* dp = &tile[row * G1S + q * 4];
            dp[0] = v.x; dp[1] = v.y; dp[2] = v.z; dp[3] = v.w;
        }
        __syncthreads();
        float f[16];
#pragma unroll
        for (int kk = 0; kk < 16; ++kk)
            f[kk] = tile[lane * G1S + kh * 16 + kk];
        const float* wp = W1 + (k0 + kh * 16) * D_H + cbase;   // wave-uniform
#pragma unroll
        for (int kk = 0; kk < 16; ++kk) {
#pragma unroll
            for (int c = 0; c < 16; ++c)
                acc[c] = fmaf(f[kk], wp[kk * D_H + c], acc[c]);
        }
    }
    // combine the two K-halves
    if (kh == 1) {
#pragma unroll
        for (int c = 0; c < 16; ++c) part[wq][c][lane] = acc[c];
    }
    __syncthreads();
    if (kh == 0) {
        int n = n0 + lane;
        if (n < N_NODES) {
            float no = norm_out[n];
#pragma unroll
            for (int c = 0; c < 16; ++c) acc[c] = (acc[c] + part[wq][c][lane]) * no;
            float* hp = h1 + n * D_H + cbase;
#pragma unroll
            for (int c0 = 0; c0 < 16; c0 += 4)
                *(float4*)(hp + c0) = make_float4(acc[c0], acc[c0 + 1], acc[c0 + 2], acc[c0 + 3]);
        }
    }
}

// ---------------- agg1: g[n][:] = relu(sum_e h1[ssrc[e]][:] * ni + b1) * no ----------------
// ONE wave per node; lane = (dim-quad q, edge slot t).

__global__ void __launch_bounds__(256) agg1_kernel(const int* __restrict__ start,
                                                   const int* __restrict__ ssrc,
                                                   const float* __restrict__ h1,
                                                   const float* __restrict__ norm_in,
                                                   const float* __restrict__ norm_out,
                                                   const float* __restrict__ b1,
                                                   float* __restrict__ g) {
    const int lane = threadIdx.x & 63;
    const int q = lane & 15;
    const int t = lane >> 4;
    const int n = (int)((blockIdx.x * blockDim.x + threadIdx.x) >> 6);
    if (n >= N_NODES) return;

    int beg = __builtin_amdgcn_readfirstlane(start[n]);
    int end = __builtin_amdgcn_readfirstlane(start[n + 1]);
    float4 acc = make_float4(0.f, 0.f, 0.f, 0.f);
    for (int e = beg + t; e < end; e += 4) {
        int s = ssrc[e];
        float4 v = *(const float4*)(h1 + s * D_H + q * 4);
        acc.x += v.x; acc.y += v.y; acc.z += v.z; acc.w += v.w;
    }
    acc.x += __shfl_xor(acc.x, 16); acc.y += __shfl_xor(acc.y, 16);
    acc.z += __shfl_xor(acc.z, 16); acc.w += __shfl_xor(acc.w, 16);
    acc.x += __shfl_xor(acc.x, 32); acc.y += __shfl_xor(acc.y, 32);
    acc.z += __shfl_xor(acc.z, 32); acc.w += __shfl_xor(acc.w, 32);
    if (t == 0) {
        float ni = norm_in[n], no = norm_out[n];
        const float4 bq = *(const float4*)&b1[q * 4];
        float4 r;
        r.x = fmaxf(fmaf(acc.x, ni, bq.x), 0.f) * no;
        r.y = fmaxf(fmaf(acc.y, ni, bq.y), 0.f) * no;
        r.z = fmaxf(fmaf(acc.z, ni, bq.z), 0.f) * no;
        r.w = fmaxf(fmaf(acc.w, ni, bq.w), 0.f) * no;
        *(float4*)(g + n * D_H + q * 4) = r;
    }
}

// ---------------- GEMM2: h2[n][0:48] = dot(g[n,:64], W2p[:,0:48]) ----------------
// Same unmixed structure: f[32] hoisted, then FMA + scalar-W region.

__global__ void __launch_bounds__(512, 8) gemm2_kernel(const float* __restrict__ g,
                                                       const float* __restrict__ W2p,
                                                       float* __restrict__ h2) {
    __shared__ float tile[64 * 65];         // 16640 B
    __shared__ float part[4][12][64];       // 12288 B
    const int tid = threadIdx.x;
    const int lane = tid & 63;
    const int wq = __builtin_amdgcn_readfirstlane((tid >> 6) & 3);
    const int kh = __builtin_amdgcn_readfirstlane(tid >> 8);
    const int cbase = wq * 12;
    const int n0 = blockIdx.x * 64;

    // stage 64x64 block of g
#pragma unroll
    for (int it = 0; it < 2; ++it) {
        int idx = it * 512 + tid;           // 0..1023
        int row = idx >> 4;                 // 0..63
        int q = idx & 15;                   // 0..15
        int nr = n0 + row; if (nr >= N_NODES) nr = N_NODES - 1;
        float4 v = *(const float4*)(g + nr * D_H + q * 4);
        float* dp = &tile[row * 65 + q * 4];
        dp[0] = v.x; dp[1] = v.y; dp[2] = v.z; dp[3] = v.w;
    }
    __syncthreads();

    float f[32];
#pragma unroll
    for (int kk = 0; kk < 32; ++kk)
        f[kk] = tile[lane * 65 + kh * 32 + kk];

    float acc[12];
#pragma unroll
    for (int c = 0; c < 12; ++c) acc[c] = 0.0f;

    const float* wp = W2p + kh * 32 * D_OP + cbase;   // wave-uniform
#pragma unroll
    for (int kk = 0; kk < 32; ++kk) {
#pragma unroll
        for (int c = 0; c < 12; ++c)
            acc[c] = fmaf(f[kk], wp[kk * D_OP + c], acc[c]);
    }

    if (kh == 1) {
#pragma unroll
        for (int c = 0; c < 12; ++c) part[wq][c][lane] = acc[c];
    }
    __syncthreads();
    if (kh == 0) {
        int n = n0 + lane;
        if (n < N_NODES) {
#pragma unroll
            for (int c = 0; c < 12; ++c) acc[c] += part[wq][c][lane];
            float* hp = h2 + n * D_OP + cbase;
#pragma unroll
            for (int c0 = 0; c0 < 12; c0 += 4)
                *(float4*)(hp + c0) = make_float4(acc[c0], acc[c0 + 1], acc[c0 + 2], acc[c0 + 3]);
        }
    }
}

// ---------------- agg2: out[n][:] = (sum_e h2[ssrc[e]][:]) * ni + b2 ----------------
// ONE wave per node.

__global__ void __launch_bounds__(256) agg2_kernel(const int* __restrict__ start,
                                                   const int* __restrict__ ssrc,
                                                   const float* __restrict__ h2,
                                                   const float* __restrict__ norm_in,
                                                   const float* __restrict__ b2,
                                                   float* __restrict__ out) {
    const int lane = threadIdx.x & 63;
    const int q = lane % 12;
    const int t = lane / 12;           // 0..5; t==5 idle
    const int n = (int)((blockIdx.x * blockDim.x + threadIdx.x) >> 6);
    if (n >= N_NODES) return;

    int beg = __builtin_amdgcn_readfirstlane(start[n]);
    int end = __builtin_amdgcn_readfirstlane(start[n + 1]);
    float4 acc = make_float4(0.f, 0.f, 0.f, 0.f);
    if (t < 5) {
        for (int e = beg + t; e < end; e += 5) {
            int s = ssrc[e];
            float4 v = *(const float4*)(h2 + s * D_OP + q * 4);
            acc.x += v.x; acc.y += v.y; acc.z += v.z; acc.w += v.w;
        }
    }
    float sx = acc.x, sy = acc.y, sz = acc.z, sw = acc.w;
#pragma unroll
    for (int o = 1; o < 5; ++o) {
        sx += __shfl(acc.x, lane + o * 12, 64);
        sy += __shfl(acc.y, lane + o * 12, 64);
        sz += __shfl(acc.z, lane + o * 12, 64);
        sw += __shfl(acc.w, lane + o * 12, 64);
    }
    if (lane < 10) {
        float ni = norm_in[n];
        float4 bq = *(const float4*)&b2[lane * 4];
        float4 r;
        r.x = fmaf(sx, ni, bq.x);
        r.y = fmaf(sy, ni, bq.y);
        r.z = fmaf(sz, ni, bq.z);
        r.w = fmaf(sw, ni, bq.w);
        *(float4*)(out + (size_t)n * D_O + lane * 4) = r;
    }
}

// ----------------------------------------------------------------------------

static inline char* alignup(char* p, size_t a) {
    return (char*)(((uintptr_t)p + a - 1) & ~(uintptr_t)(a - 1));
}

extern "C" void kernel_launch(void* const* d_in, const int* in_sizes, int n_in,
                              void* d_out, int out_size, void* d_ws, size_t ws_size,
                              hipStream_t stream) {
    const float* feat = (const float*)d_in[0];
    const int*   src  = (const int*)d_in[1];
    const int*   dst  = (const int*)d_in[2];
    const float* W1   = (const float*)d_in[3];
    const float* b1   = (const float*)d_in[4];
    const float* W2   = (const float*)d_in[5];
    const float* b2   = (const float*)d_in[6];
    float* out = (float*)d_out;

    char* p = alignup((char*)d_ws, 256);
    int*   cnt_in   = (int*)p;    p = alignup(p + N_NODES * 4, 256);
    int*   start    = (int*)p;    p = alignup(p + (N_NODES + 1) * 4, 256);
    int*   blocksum = (int*)p;    p = alignup(p + 256 * 4, 256);
    float* norm_out = (float*)p;  p = alignup(p + N_NODES * 4, 256);
    float* norm_in  = (float*)p;  p = alignup(p + N_NODES * 4, 256);
    float* W2p      = (float*)p;  p = alignup(p + D_H * D_OP * 4, 256);
    int*   ssrc     = (int*)p;    p = alignup(p + N_EDGES * 4, 256);
    float* h1       = (float*)p;  p = alignup(p + (size_t)N_NODES * D_H * 4, 256);
    float* g        = (float*)p;  p = alignup(p + (size_t)N_NODES * D_H * 4, 256);
    float* h2       = h1;         // h1 dead after agg1

    // u16 partial-count matrix [NB_H][N_NODES] = 25.6 MB, aliasing h1+g.
    u16* part = (u16*)h1;

    hist_part_kernel<<<NB_H, NT_H, 0, stream>>>(src, part);
    reduce_nout_kernel<<<SCAN_NB, 256, 0, stream>>>(part, norm_out);

    hist_part_kernel<<<NB_H, NT_H, 0, stream>>>(dst, part);
    colscan_kernel<<<SCAN_NB, 256, 0, stream>>>(part, cnt_in, norm_in);

    scan1_kernel<<<SCAN_NB, 256, 0, stream>>>(cnt_in, start, blocksum);
    scan2_kernel<<<1, 256, 0, stream>>>(blocksum);
    scan3_kernel<<<SCAN_NB, 256, 0, stream>>>(start, blocksum);

    scatter2_kernel<<<NB_H, NT_H, 0, stream>>>(src, dst, start, part, ssrc);
    padw2_kernel<<<(D_H * D_OP + 255) / 256, 256, 0, stream>>>(W2, W2p);

    gemm1_kernel<<<(N_NODES + 63) / 64, 512, 0, stream>>>(feat, W1, norm_out, h1);
    agg1_kernel<<<(N_NODES + 3) / 4, 256, 0, stream>>>(start, ssrc, h1, norm_in, norm_out, b1, g);

    gemm2_kernel<<<(N_NODES + 63) / 64, 512, 0, stream>>>(g, W2p, h2);
    agg2_kernel<<<(N_NODES + 3) / 4, 256, 0, stream>>>(start, ssrc, h2, norm_in, b2, out);
}

// Round 9
// 178.499 us; speedup vs baseline: 1.5265x; 1.0756x over previous
//
#include <hip/hip_runtime.h>
#include <stdint.h>

#define N_NODES 50000
#define N_EDGES 800000
#define D_IN    256
#define D_H     64
#define D_O     40
#define D_OP    48   // h2 padded row stride

// CSR build geometry: 256 blocks x 3125-edge slices; node space covered in
// 2 LDS passes of 25000 nodes packed 2-per-u32 (50 KB LDS, no global atomics).
#define NB_H   256
#define NT_H   512
#define EPB    (N_EDGES / NB_H)   // 3125
#define BINS_N 25000              // nodes per pass
#define BINS_W 12500              // u32 words (2 nodes each)
#define NPASS  2

typedef unsigned int u32;
typedef unsigned short u16;

// ---------------- per-block partial histograms, src and dst in one launch ----------------

__global__ void __launch_bounds__(NT_H) hist_both_kernel(const int* __restrict__ src,
                                                         const int* __restrict__ dst,
                                                         u16* __restrict__ part_s,
                                                         u16* __restrict__ part_d) {
    __shared__ u32 bins[BINS_W];
    const int gb = blockIdx.x;
    const int b = (gb < NB_H) ? gb : gb - NB_H;
    const int* __restrict__ idx = (gb < NB_H) ? src : dst;
    u16* __restrict__ part = (gb < NB_H) ? part_s : part_d;
    const int e0 = b * EPB;
    const int e1 = (e0 + EPB < N_EDGES) ? e0 + EPB : N_EDGES;
    for (int pass = 0; pass < NPASS; ++pass) {
        const int base = pass * BINS_N;
        for (int i = threadIdx.x; i < BINS_W; i += NT_H) bins[i] = 0;
        __syncthreads();
        for (int e = e0 + threadIdx.x; e < e1; e += NT_H) {
            int v = idx[e] - base;
            if ((u32)v < (u32)BINS_N)
                atomicAdd(&bins[v >> 1], (v & 1) ? 0x10000u : 1u);
        }
        __syncthreads();
        for (int i = threadIdx.x; i < BINS_N; i += NT_H) {
            u32 w = bins[i >> 1];
            part[(size_t)b * N_NODES + base + i] = (u16)((i & 1) ? (w >> 16) : (w & 0xFFFFu));
        }
        __syncthreads();
    }
}

// ---------------- norm_out = rsqrt(max(col-sum of src partials, 1)) ----------------

__global__ void reduce_nout_kernel(const u16* __restrict__ part, float* __restrict__ norm_out) {
    int n = blockIdx.x * blockDim.x + threadIdx.x;
    if (n < N_NODES) {
        u32 acc = 0;
#pragma unroll 8
        for (int b = 0; b < NB_H; ++b) acc += part[(size_t)b * N_NODES + n];
        norm_out[n] = rsqrtf(fmaxf((float)acc, 1.0f));
    }
}

// ---------------- exclusive column-prefix of dst partials (-> off), cnt_in, norm_in ----------------

__global__ void colscan_kernel(u16* __restrict__ part, int* __restrict__ cnt_in,
                               float* __restrict__ norm_in) {
    int n = blockIdx.x * blockDim.x + threadIdx.x;
    if (n < N_NODES) {
        u32 acc = 0;
#pragma unroll 8
        for (int b = 0; b < NB_H; ++b) {
            size_t i = (size_t)b * N_NODES + n;
            u32 t = part[i];
            part[i] = (u16)acc;
            acc += t;
        }
        cnt_in[n] = (int)acc;
        norm_in[n] = rsqrtf(fmaxf((float)acc, 1.0f));
    }
}

// ---------------- exclusive scan of cnt_in -> start[] ----------------

#define SCAN_NB ((N_NODES + 255) / 256)   // 196

__global__ void scan1_kernel(const int* __restrict__ cnt, int* __restrict__ start,
                             int* __restrict__ blocksum) {
    __shared__ int tmp[256];
    int i = blockIdx.x * 256 + threadIdx.x;
    int v = (i < N_NODES) ? cnt[i] : 0;
    tmp[threadIdx.x] = v;
    __syncthreads();
    for (int off = 1; off < 256; off <<= 1) {
        int t = (threadIdx.x >= off) ? tmp[threadIdx.x - off] : 0;
        __syncthreads();
        tmp[threadIdx.x] += t;
        __syncthreads();
    }
    if (i < N_NODES) start[i] = tmp[threadIdx.x] - v;
    if (threadIdx.x == 255) blocksum[blockIdx.x] = tmp[255];
}

__global__ void scan2_kernel(int* __restrict__ blocksum) {
    __shared__ int tmp[256];
    int v = (threadIdx.x < SCAN_NB) ? blocksum[threadIdx.x] : 0;
    tmp[threadIdx.x] = v;
    __syncthreads();
    for (int off = 1; off < 256; off <<= 1) {
        int t = (threadIdx.x >= off) ? tmp[threadIdx.x - off] : 0;
        __syncthreads();
        tmp[threadIdx.x] += t;
        __syncthreads();
    }
    blocksum[threadIdx.x] = tmp[threadIdx.x] - v;
}

__global__ void scan3_kernel(int* __restrict__ start, const int* __restrict__ blocksum) {
    int i = blockIdx.x * 256 + threadIdx.x;
    if (i < N_NODES) start[i] += blocksum[i >> 8];
    if (i == 0) start[N_NODES] = N_EDGES;
}

// ---------------- scatter edges into CSR order (packed LDS cursors) ----------------

__global__ void __launch_bounds__(NT_H) scatter2_kernel(const int* __restrict__ src,
                                                        const int* __restrict__ dst,
                                                        const int* __restrict__ start,
                                                        const u16* __restrict__ off,
                                                        int* __restrict__ ssrc) {
    __shared__ u32 cur[BINS_W];
    const int b = blockIdx.x;
    const int e0 = b * EPB;
    const int e1 = (e0 + EPB < N_EDGES) ? e0 + EPB : N_EDGES;
    for (int pass = 0; pass < NPASS; ++pass) {
        const int base = pass * BINS_N;
        for (int i = threadIdx.x; i < BINS_W; i += NT_H) cur[i] = 0;
        __syncthreads();
        for (int e = e0 + threadIdx.x; e < e1; e += NT_H) {
            int d = dst[e];
            int r = d - base;
            if ((u32)r < (u32)BINS_N) {
                u32 old = atomicAdd(&cur[r >> 1], (r & 1) ? 0x10000u : 1u);
                int c = (int)((r & 1) ? (old >> 16) : (old & 0xFFFFu));
                int pos = start[d] + (int)off[(size_t)b * N_NODES + d] + c;
                ssrc[pos] = src[e];
            }
        }
        __syncthreads();
    }
}

// ---------------- W2 zero-padded to [64][48] ----------------

__global__ void padw2_kernel(const float* __restrict__ W2, float* __restrict__ W2p) {
    int i = blockIdx.x * blockDim.x + threadIdx.x;
    if (i < D_H * D_OP) {
        int k = i / D_OP, j = i - k * D_OP;
        W2p[i] = (j < D_O) ? W2[k * D_O + j] : 0.0f;
    }
}

// ---------------- GEMM1: h1[n][j] = norm_out[n] * dot(feat[n,:], W1[:,j]) ----------------
// 512 thr = 8 waves: (wave&3) = 16-col group, (wave>>2) = K-half.
// Double-buffered reg-staging: issue chunk t+1's global loads before the FMA
// block of chunk t, ds_write to the other buffer after, ONE barrier per chunk.
// Stride 36 -> f[16] read as 4x ds_read_b128, conflict-optimal.

#define G1S 36

__global__ void __launch_bounds__(512, 4) gemm1_kernel(const float* __restrict__ feat,
                                                       const float* __restrict__ W1,
                                                       const float* __restrict__ norm_out,
                                                       float* __restrict__ h1) {
    __shared__ float tile[2][64 * G1S];     // 18432 B
    __shared__ float part[4][16][64];       // 16384 B
    const int tid = threadIdx.x;
    const int lane = tid & 63;
    const int wq = __builtin_amdgcn_readfirstlane((tid >> 6) & 3);
    const int kh = __builtin_amdgcn_readfirstlane(tid >> 8);   // 0 or 1
    const int cbase = wq * 16;
    const int n0 = blockIdx.x * 64;

    const int row = tid >> 3;               // 0..63 (staging role)
    const int q = tid & 7;                  // 0..7
    int nr = n0 + row; if (nr >= N_NODES) nr = N_NODES - 1;
    const float* fsrc = feat + nr * D_IN + q * 4;

    float acc[16];
#pragma unroll
    for (int c = 0; c < 16; ++c) acc[c] = 0.0f;

    // prologue: stage chunk 0
    {
        float4 v = *(const float4*)(fsrc);
        *(float4*)&tile[0][row * G1S + q * 4] = v;
    }
    __syncthreads();

#pragma unroll
    for (int t = 0; t < 8; ++t) {
        const int cur = t & 1;
        float4 vn;
        if (t < 7)
            vn = *(const float4*)(fsrc + (t + 1) * 32);   // issue next-chunk load

        float4 f4[4];
#pragma unroll
        for (int j = 0; j < 4; ++j)
            f4[j] = *(const float4*)&tile[cur][lane * G1S + kh * 16 + j * 4];

        const float* wp = W1 + (t * 32 + kh * 16) * D_H + cbase;   // wave-uniform
        const float* fv = (const float*)f4;
#pragma unroll
        for (int kk = 0; kk < 16; ++kk) {
#pragma unroll
            for (int c = 0; c < 16; ++c)
                acc[c] = fmaf(fv[kk], wp[kk * D_H + c], acc[c]);
        }

        if (t < 7)
            *(float4*)&tile[cur ^ 1][row * G1S + q * 4] = vn;
        __syncthreads();
    }

    // combine the two K-halves
    if (kh == 1) {
#pragma unroll
        for (int c = 0; c < 16; ++c) part[wq][c][lane] = acc[c];
    }
    __syncthreads();
    if (kh == 0) {
        int n = n0 + lane;
        if (n < N_NODES) {
            float no = norm_out[n];
#pragma unroll
            for (int c = 0; c < 16; ++c) acc[c] = (acc[c] + part[wq][c][lane]) * no;
            float* hp = h1 + n * D_H + cbase;
#pragma unroll
            for (int c0 = 0; c0 < 16; c0 += 4)
                *(float4*)(hp + c0) = make_float4(acc[c0], acc[c0 + 1], acc[c0 + 2], acc[c0 + 3]);
        }
    }
}

// ---------------- agg1: g[n][:] = relu(sum_e h1[ssrc[e]][:] * ni + b1) * no ----------------
// ONE wave per node; lane = (dim-quad q, edge slot t); 2 edges per slot per iter.

__global__ void __launch_bounds__(256) agg1_kernel(const int* __restrict__ start,
                                                   const int* __restrict__ ssrc,
                                                   const float* __restrict__ h1,
                                                   const float* __restrict__ norm_in,
                                                   const float* __restrict__ norm_out,
                                                   const float* __restrict__ b1,
                                                   float* __restrict__ g) {
    const int lane = threadIdx.x & 63;
    const int q = lane & 15;
    const int t = lane >> 4;
    const int n = (int)((blockIdx.x * blockDim.x + threadIdx.x) >> 6);
    if (n >= N_NODES) return;

    int beg = __builtin_amdgcn_readfirstlane(start[n]);
    int end = __builtin_amdgcn_readfirstlane(start[n + 1]);
    float4 acc = make_float4(0.f, 0.f, 0.f, 0.f);
    for (int e = beg + t; e < end; e += 8) {
        int s0 = ssrc[e];
        float4 v0 = *(const float4*)(h1 + s0 * D_H + q * 4);
        if (e + 4 < end) {
            int s1 = ssrc[e + 4];
            float4 v1 = *(const float4*)(h1 + s1 * D_H + q * 4);
            acc.x += v1.x; acc.y += v1.y; acc.z += v1.z; acc.w += v1.w;
        }
        acc.x += v0.x; acc.y += v0.y; acc.z += v0.z; acc.w += v0.w;
    }
    acc.x += __shfl_xor(acc.x, 16); acc.y += __shfl_xor(acc.y, 16);
    acc.z += __shfl_xor(acc.z, 16); acc.w += __shfl_xor(acc.w, 16);
    acc.x += __shfl_xor(acc.x, 32); acc.y += __shfl_xor(acc.y, 32);
    acc.z += __shfl_xor(acc.z, 32); acc.w += __shfl_xor(acc.w, 32);
    if (t == 0) {
        float ni = norm_in[n], no = norm_out[n];
        const float4 bq = *(const float4*)&b1[q * 4];
        float4 r;
        r.x = fmaxf(fmaf(acc.x, ni, bq.x), 0.f) * no;
        r.y = fmaxf(fmaf(acc.y, ni, bq.y), 0.f) * no;
        r.z = fmaxf(fmaf(acc.z, ni, bq.z), 0.f) * no;
        r.w = fmaxf(fmaf(acc.w, ni, bq.w), 0.f) * no;
        *(float4*)(g + n * D_H + q * 4) = r;
    }
}

// ---------------- GEMM2: h2[n][0:48] = dot(g[n,:64], W2p[:,0:48]) ----------------

__global__ void __launch_bounds__(512, 8) gemm2_kernel(const float* __restrict__ g,
                                                       const float* __restrict__ W2p,
                                                       float* __restrict__ h2) {
    __shared__ float tile[64 * 65];         // 16640 B
    __shared__ float part[4][12][64];       // 12288 B
    const int tid = threadIdx.x;
    const int lane = tid & 63;
    const int wq = __builtin_amdgcn_readfirstlane((tid >> 6) & 3);
    const int kh = __builtin_amdgcn_readfirstlane(tid >> 8);
    const int cbase = wq * 12;
    const int n0 = blockIdx.x * 64;

    // stage 64x64 block of g
#pragma unroll
    for (int it = 0; it < 2; ++it) {
        int idx = it * 512 + tid;           // 0..1023
        int row = idx >> 4;                 // 0..63
        int q = idx & 15;                   // 0..15
        int nr = n0 + row; if (nr >= N_NODES) nr = N_NODES - 1;
        float4 v = *(const float4*)(g + nr * D_H + q * 4);
        float* dp = &tile[row * 65 + q * 4];
        dp[0] = v.x; dp[1] = v.y; dp[2] = v.z; dp[3] = v.w;
    }
    __syncthreads();

    float f[32];
#pragma unroll
    for (int kk = 0; kk < 32; ++kk)
        f[kk] = tile[lane * 65 + kh * 32 + kk];

    float acc[12];
#pragma unroll
    for (int c = 0; c < 12; ++c) acc[c] = 0.0f;

    const float* wp = W2p + kh * 32 * D_OP + cbase;   // wave-uniform
#pragma unroll
    for (int kk = 0; kk < 32; ++kk) {
#pragma unroll
        for (int c = 0; c < 12; ++c)
            acc[c] = fmaf(f[kk], wp[kk * D_OP + c], acc[c]);
    }

    if (kh == 1) {
#pragma unroll
        for (int c = 0; c < 12; ++c) part[wq][c][lane] = acc[c];
    }
    __syncthreads();
    if (kh == 0) {
        int n = n0 + lane;
        if (n < N_NODES) {
#pragma unroll
            for (int c = 0; c < 12; ++c) acc[c] += part[wq][c][lane];
            float* hp = h2 + n * D_OP + cbase;
#pragma unroll
            for (int c0 = 0; c0 < 12; c0 += 4)
                *(float4*)(hp + c0) = make_float4(acc[c0], acc[c0 + 1], acc[c0 + 2], acc[c0 + 3]);
        }
    }
}

// ---------------- agg2: out[n][:] = (sum_e h2[ssrc[e]][:]) * ni + b2 ----------------
// ONE wave per node; 2 edges per slot per iter.

__global__ void __launch_bounds__(256) agg2_kernel(const int* __restrict__ start,
                                                   const int* __restrict__ ssrc,
                                                   const float* __restrict__ h2,
                                                   const float* __restrict__ norm_in,
                                                   const float* __restrict__ b2,
                                                   float* __restrict__ out) {
    const int lane = threadIdx.x & 63;
    const int q = lane % 12;
    const int t = lane / 12;           // 0..5; t==5 idle
    const int n = (int)((blockIdx.x * blockDim.x + threadIdx.x) >> 6);
    if (n >= N_NODES) return;

    int beg = __builtin_amdgcn_readfirstlane(start[n]);
    int end = __builtin_amdgcn_readfirstlane(start[n + 1]);
    float4 acc = make_float4(0.f, 0.f, 0.f, 0.f);
    if (t < 5) {
        for (int e = beg + t; e < end; e += 10) {
            int s0 = ssrc[e];
            float4 v0 = *(const float4*)(h2 + s0 * D_OP + q * 4);
            if (e + 5 < end) {
                int s1 = ssrc[e + 5];
                float4 v1 = *(const float4*)(h2 + s1 * D_OP + q * 4);
                acc.x += v1.x; acc.y += v1.y; acc.z += v1.z; acc.w += v1.w;
            }
            acc.x += v0.x; acc.y += v0.y; acc.z += v0.z; acc.w += v0.w;
        }
    }
    float sx = acc.x, sy = acc.y, sz = acc.z, sw = acc.w;
#pragma unroll
    for (int o = 1; o < 5; ++o) {
        sx += __shfl(acc.x, lane + o * 12, 64);
        sy += __shfl(acc.y, lane + o * 12, 64);
        sz += __shfl(acc.z, lane + o * 12, 64);
        sw += __shfl(acc.w, lane + o * 12, 64);
    }
    if (lane < 10) {
        float ni = norm_in[n];
        float4 bq = *(const float4*)&b2[lane * 4];
        float4 r;
        r.x = fmaf(sx, ni, bq.x);
        r.y = fmaf(sy, ni, bq.y);
        r.z = fmaf(sz, ni, bq.z);
        r.w = fmaf(sw, ni, bq.w);
        *(float4*)(out + (size_t)n * D_O + lane * 4) = r;
    }
}

// ----------------------------------------------------------------------------

static inline char* alignup(char* p, size_t a) {
    return (char*)(((uintptr_t)p + a - 1) & ~(uintptr_t)(a - 1));
}

extern "C" void kernel_launch(void* const* d_in, const int* in_sizes, int n_in,
                              void* d_out, int out_size, void* d_ws, size_t ws_size,
                              hipStream_t stream) {
    const float* feat = (const float*)d_in[0];
    const int*   src  = (const int*)d_in[1];
    const int*   dst  = (const int*)d_in[2];
    const float* W1   = (const float*)d_in[3];
    const float* b1   = (const float*)d_in[4];
    const float* W2   = (const float*)d_in[5];
    const float* b2   = (const float*)d_in[6];
    float* out = (float*)d_out;

    char* p = alignup((char*)d_ws, 256);
    int*   cnt_in   = (int*)p;    p = alignup(p + N_NODES * 4, 256);
    int*   start    = (int*)p;    p = alignup(p + (N_NODES + 1) * 4, 256);
    int*   blocksum = (int*)p;    p = alignup(p + 256 * 4, 256);
    float* norm_out = (float*)p;  p = alignup(p + N_NODES * 4, 256);
    float* norm_in  = (float*)p;  p = alignup(p + N_NODES * 4, 256);
    float* W2p      = (float*)p;  p = alignup(p + D_H * D_OP * 4, 256);
    int*   ssrc     = (int*)p;    p = alignup(p + N_EDGES * 4, 256);
    float* h1       = (float*)p;  p = alignup(p + (size_t)N_NODES * D_H * 4, 256);
    float* g        = (float*)p;  p = alignup(p + (size_t)N_NODES * D_H * 4, 256);
    u16*   part_s   = (u16*)p;    p = alignup(p + (size_t)NB_H * N_NODES * 2, 256);
    u16*   part_d   = (u16*)p;    p = alignup(p + (size_t)NB_H * N_NODES * 2, 256);
    float* h2       = h1;         // h1 dead after agg1; N*48 <= N*64

    hist_both_kernel<<<2 * NB_H, NT_H, 0, stream>>>(src, dst, part_s, part_d);
    reduce_nout_kernel<<<SCAN_NB, 256, 0, stream>>>(part_s, norm_out);
    colscan_kernel<<<SCAN_NB, 256, 0, stream>>>(part_d, cnt_in, norm_in);

    scan1_kernel<<<SCAN_NB, 256, 0, stream>>>(cnt_in, start, blocksum);
    scan2_kernel<<<1, 256, 0, stream>>>(blocksum);
    scan3_kernel<<<SCAN_NB, 256, 0, stream>>>(start, blocksum);

    scatter2_kernel<<<NB_H, NT_H, 0, stream>>>(src, dst, start, part_d, ssrc);
    padw2_kernel<<<(D_H * D_OP + 255) / 256, 256, 0, stream>>>(W2, W2p);

    gemm1_kernel<<<(N_NODES + 63) / 64, 512, 0, stream>>>(feat, W1, norm_out, h1);
    agg1_kernel<<<(N_NODES + 3) / 4, 256, 0, stream>>>(start, ssrc, h1, norm_in, norm_out, b1, g);

    gemm2_kernel<<<(N_NODES + 63) / 64, 512, 0, stream>>>(g, W2p, h2);
    agg2_kernel<<<(N_NODES + 3) / 4, 256, 0, stream>>>(start, ssrc, h2, norm_in, b2, out);
}